// Round 1
// baseline (1452.259 us; speedup 1.0000x reference)
//
#include <hip/hip_runtime.h>

#define HW      16384
#define C_DIM   256
#define S_DIM   256
#define T_K     128
#define NH      8
#define DH      32
#define QKV_ST  768
#define B_DIM   2
#define SCALE_F 0.17677669529663687f

// ---------------------------------------------------------------------------
// sortable key: larger key <=> larger float (no NaNs in inputs)
__device__ __forceinline__ unsigned sortkey(float f) {
    unsigned u = __float_as_uint(f);
    return (u & 0x80000000u) ? ~u : (u | 0x80000000u);
}

// ---------------------------------------------------------------------------
// Kernel 1: per-pixel LayerNorm statistics (mean, rsqrt(var+eps)) over C
__global__ void ln_stats_kernel(const float* __restrict__ x,
                                float* __restrict__ mu,
                                float* __restrict__ rsig) {
    int p = blockIdx.x * blockDim.x + threadIdx.x;   // 0 .. B*HW-1
    int b = p >> 14;
    int n = p & (HW - 1);
    const float* xb = x + (size_t)b * C_DIM * HW + n;
    float s = 0.f, ss = 0.f;
#pragma unroll 8
    for (int c = 0; c < C_DIM; c++) {
        float v = xb[(size_t)c * HW];
        s += v; ss += v * v;
    }
    float m   = s * (1.f / C_DIM);
    float var = fmaxf(ss * (1.f / C_DIM) - m * m, 0.f);
    mu[p]   = m;
    rsig[p] = rsqrtf(var + 1e-5f);
}

// ---------------------------------------------------------------------------
// Kernel 2: fused LN + QKV projection.
// out[b][n][o] = sum_c W[o][c] * ((x[b][c][n]-mu)*rsig*g[c] + beta[c])
// W rows: o<256 -> wq[o], o<512 -> wk[o-256], else wv[o-512].
// Output layout (B, HW, 768) so gathers read contiguous segments.
__launch_bounds__(256)
__global__ void qkv_gemm_kernel(const float* __restrict__ x,
                                const float* __restrict__ wq,
                                const float* __restrict__ wk,
                                const float* __restrict__ wv,
                                const float* __restrict__ g,
                                const float* __restrict__ beta,
                                const float* __restrict__ mu,
                                const float* __restrict__ rsig,
                                float* __restrict__ qkv) {
    int b  = blockIdx.z;
    int n0 = blockIdx.x * 64;
    int o0 = blockIdx.y * 64;
    int tid = threadIdx.x;
    int tx = tid & 15;    // o micro-index
    int ty = tid >> 4;    // n micro-index

    __shared__ float Xs[16][64];   // [c][n]
    __shared__ float Os[16][68];   // [c][o], padded

    const float* xb = x + (size_t)b * C_DIM * HW;
    float acc[4][4];
#pragma unroll
    for (int j = 0; j < 4; j++)
#pragma unroll
        for (int i = 0; i < 4; i++) acc[j][i] = 0.f;

    // per-thread LN constants for the n-columns this thread stages
    int nl_stage = tid & 63;
    int n_stage  = n0 + nl_stage;
    float m_st = mu[b * HW + n_stage];
    float r_st = rsig[b * HW + n_stage];

    for (int c0 = 0; c0 < C_DIM; c0 += 16) {
        // stage W tile: thread -> (o_local = tid/4, c_off = (tid%4)*4)
        {
            int ol = tid >> 2;
            int cc = (tid & 3) * 4;
            int o  = o0 + ol;
            const float* wrow;
            if (o < 256)       wrow = wq + (size_t)o * 256;
            else if (o < 512)  wrow = wk + (size_t)(o - 256) * 256;
            else               wrow = wv + (size_t)(o - 512) * 256;
            float4 w4 = *(const float4*)(wrow + c0 + cc);
            Os[cc + 0][ol] = w4.x;
            Os[cc + 1][ol] = w4.y;
            Os[cc + 2][ol] = w4.z;
            Os[cc + 3][ol] = w4.w;
        }
        // stage X tile with LN applied: thread -> (c row group, n column)
        {
            int crow = tid >> 6;   // 0..3
#pragma unroll
            for (int i = 0; i < 4; i++) {
                int cl = crow + i * 4;
                int c  = c0 + cl;
                float xv = xb[(size_t)c * HW + n_stage];
                Xs[cl][nl_stage] = (xv - m_st) * r_st * g[c] + beta[c];
            }
        }
        __syncthreads();
#pragma unroll
        for (int c = 0; c < 16; c++) {
            float ov[4], xv[4];
#pragma unroll
            for (int i = 0; i < 4; i++) ov[i] = Os[c][tx + 16 * i];
#pragma unroll
            for (int j = 0; j < 4; j++) xv[j] = Xs[c][ty + 16 * j];
#pragma unroll
            for (int j = 0; j < 4; j++)
#pragma unroll
                for (int i = 0; i < 4; i++) acc[j][i] += xv[j] * ov[i];
        }
        __syncthreads();
    }

    float* outb = qkv + (size_t)b * HW * QKV_ST;
#pragma unroll
    for (int j = 0; j < 4; j++) {
        size_t row = (size_t)(n0 + ty + 16 * j) * QKV_ST + o0;
#pragma unroll
        for (int i = 0; i < 4; i++) outb[row + tx + 16 * i] = acc[j][i];
    }
}

// ---------------------------------------------------------------------------
// Kernel 3: exact top-128 per (b,s) row via MSB-first radix select.
// Order of output pairs is arbitrary (downstream math is permutation-equivariant).
__launch_bounds__(256)
__global__ void topk_kernel(const float* __restrict__ aff,
                            float* __restrict__ sims,
                            int* __restrict__ idx) {
    int s = blockIdx.x, b = blockIdx.y;
    int tid = threadIdx.x;
    const float* row = aff + ((size_t)b * S_DIM + s) * HW;

    __shared__ unsigned hist[256];
    __shared__ unsigned s_sel, s_above;
    __shared__ int cHi, cEq;

    unsigned prefix = 0;
    int kneed = T_K;

    for (int shift = 24; shift >= 0; shift -= 8) {
        hist[tid] = 0;
        __syncthreads();
        unsigned mask = (shift == 24) ? 0u : (0xFFFFFFFFu << (shift + 8));
        for (int n = tid; n < HW; n += 256) {
            unsigned u = sortkey(row[n]);
            if ((u & mask) == prefix)
                atomicAdd(&hist[(u >> shift) & 255], 1u);
        }
        __syncthreads();
        if (tid == 0) {
            unsigned cum = 0;
            for (int bin = 255; bin >= 0; --bin) {
                unsigned c = hist[bin];
                if (cum + c >= (unsigned)kneed) { s_sel = (unsigned)bin; s_above = cum; break; }
                cum += c;
            }
        }
        __syncthreads();
        prefix |= (s_sel << shift);
        kneed  -= (int)s_above;
        __syncthreads();
    }

    unsigned T = prefix;          // 128th-largest key
    int nGt = T_K - kneed;        // count strictly greater
    if (tid == 0) { cHi = 0; cEq = 0; }
    __syncthreads();

    float* so = sims + ((size_t)b * S_DIM + s) * T_K;
    int*   io = idx  + ((size_t)b * S_DIM + s) * T_K;
    for (int n = tid; n < HW; n += 256) {
        float v = row[n];
        unsigned u = sortkey(v);
        if (u > T) {
            int p = atomicAdd(&cHi, 1);
            so[p] = v; io[p] = n;
        } else if (u == T) {
            int p = atomicAdd(&cEq, 1);
            if (p < kneed) { so[nGt + p] = v; io[nGt + p] = n; }
        }
    }
}

// ---------------------------------------------------------------------------
// Kernel 4: attention per (b, s, h). One thread per query row t (128 threads).
// Online softmax in registers; K and sims-weighted V staged in LDS.
// Result rows scaled by sims_t and atomically added into acc (B, HW, C).
__launch_bounds__(128)
__global__ void attn_kernel(const float* __restrict__ qkv,
                            const float* __restrict__ sims,
                            const int* __restrict__ idx,
                            float* __restrict__ acc) {
    int s = blockIdx.x, h = blockIdx.y, b = blockIdx.z;
    int tid = threadIdx.x;

    __shared__ float4 k4[T_K][8];
    __shared__ float4 v4[T_K][8];
    __shared__ float  sim_s[T_K];
    __shared__ int    idx_s[T_K];

    const float* simrow = sims + ((size_t)b * S_DIM + s) * T_K;
    const int*   idxrow = idx  + ((size_t)b * S_DIM + s) * T_K;
    sim_s[tid] = simrow[tid];
    idx_s[tid] = idxrow[tid];
    __syncthreads();

    const float* qkvb = qkv + (size_t)b * HW * QKV_ST;
    int co = h * DH;

    // stage K and sims-weighted V: 8 threads per row, float4 each
    for (int r0 = 0; r0 < T_K; r0 += 16) {
        int r  = r0 + (tid >> 3);
        int c4 = tid & 7;
        const float* base = qkvb + (size_t)idx_s[r] * QKV_ST;
        float4 kk = *(const float4*)(base + 256 + co + c4 * 4);
        float4 vv = *(const float4*)(base + 512 + co + c4 * 4);
        float sm = sim_s[r];
        vv.x *= sm; vv.y *= sm; vv.z *= sm; vv.w *= sm;
        k4[r][c4] = kk;
        v4[r][c4] = vv;
    }

    // this thread's q row
    float4 q[8];
    {
        const float* base = qkvb + (size_t)idx_s[tid] * QKV_ST + co;
#pragma unroll
        for (int j = 0; j < 8; j++) q[j] = *(const float4*)(base + j * 4);
    }
    __syncthreads();

    float m = -1e30f, l = 0.f;
    float4 o[8];
#pragma unroll
    for (int j = 0; j < 8; j++) o[j] = make_float4(0.f, 0.f, 0.f, 0.f);

    for (int u = 0; u < T_K; u++) {
        float sd = 0.f;
#pragma unroll
        for (int j = 0; j < 8; j++) {
            float4 kk = k4[u][j];
            sd += q[j].x * kk.x + q[j].y * kk.y + q[j].z * kk.z + q[j].w * kk.w;
        }
        sd *= SCALE_F;
        float mn   = fmaxf(m, sd);
        float corr = __expf(m - mn);   // exp(-inf)=0 on first iter
        float p    = __expf(sd - mn);
        l = l * corr + p;
        m = mn;
#pragma unroll
        for (int j = 0; j < 8; j++) {
            float4 vv = v4[u][j];
            o[j].x = o[j].x * corr + p * vv.x;
            o[j].y = o[j].y * corr + p * vv.y;
            o[j].z = o[j].z * corr + p * vv.z;
            o[j].w = o[j].w * corr + p * vv.w;
        }
    }

    float invl = sim_s[tid] / l;
    float* arow = acc + ((size_t)b * HW + idx_s[tid]) * C_DIM + co;
#pragma unroll
    for (int j = 0; j < 8; j++) {
        atomicAdd(arow + j * 4 + 0, o[j].x * invl);
        atomicAdd(arow + j * 4 + 1, o[j].y * invl);
        atomicAdd(arow + j * 4 + 2, o[j].z * invl);
        atomicAdd(arow + j * 4 + 3, o[j].w * invl);
    }
}

// ---------------------------------------------------------------------------
// Kernel 5: out[b][c][n] = v[b][n][c] + acc[b][n][c]  (transpose via LDS tile)
__launch_bounds__(256)
__global__ void transpose_add_kernel(const float* __restrict__ qkv,
                                     const float* __restrict__ acc,
                                     float* __restrict__ out) {
    int b  = blockIdx.z;
    int n0 = blockIdx.x * 32;
    int c0 = blockIdx.y * 32;
    int x = threadIdx.x & 31;
    int y = threadIdx.x >> 5;   // 0..7

    __shared__ float t[32][33];
#pragma unroll
    for (int r = 0; r < 4; r++) {
        int n = n0 + y + 8 * r;
        size_t row = (size_t)b * HW + n;
        t[y + 8 * r][x] = qkv[row * QKV_ST + 512 + c0 + x] + acc[row * C_DIM + c0 + x];
    }
    __syncthreads();
#pragma unroll
    for (int r = 0; r < 4; r++) {
        int c = c0 + y + 8 * r;
        out[((size_t)b * C_DIM + c) * HW + n0 + x] = t[x][y + 8 * r];
    }
}

// ---------------------------------------------------------------------------
extern "C" void kernel_launch(void* const* d_in, const int* in_sizes, int n_in,
                              void* d_out, int out_size, void* d_ws, size_t ws_size,
                              hipStream_t stream) {
    const float* x    = (const float*)d_in[0];
    const float* aff  = (const float*)d_in[1];
    const float* g    = (const float*)d_in[2];
    const float* beta = (const float*)d_in[3];
    const float* wq   = (const float*)d_in[4];
    const float* wk   = (const float*)d_in[5];
    const float* wv   = (const float*)d_in[6];
    float* out = (float*)d_out;

    float* ws   = (float*)d_ws;
    float* qkv  = ws;                                         // B*HW*768
    float* mu   = qkv  + (size_t)B_DIM * HW * QKV_ST;         // B*HW
    float* rsig = mu   + (size_t)B_DIM * HW;                  // B*HW
    float* simsb= rsig + (size_t)B_DIM * HW;                  // B*S*T
    float* acc  = simsb+ (size_t)B_DIM * S_DIM * T_K;         // B*HW*C
    int*   idxb = (int*)(acc + (size_t)B_DIM * HW * C_DIM);   // B*S*T ints

    hipMemsetAsync(acc, 0, (size_t)B_DIM * HW * C_DIM * sizeof(float), stream);

    ln_stats_kernel<<<dim3(B_DIM * HW / 256), 256, 0, stream>>>(x, mu, rsig);
    qkv_gemm_kernel<<<dim3(HW / 64, QKV_ST / 64, B_DIM), 256, 0, stream>>>(
        x, wq, wk, wv, g, beta, mu, rsig, qkv);
    topk_kernel<<<dim3(S_DIM, B_DIM), 256, 0, stream>>>(aff, simsb, idxb);
    attn_kernel<<<dim3(S_DIM, NH, B_DIM), 128, 0, stream>>>(qkv, simsb, idxb, acc);
    transpose_add_kernel<<<dim3(HW / 32, C_DIM / 32, B_DIM), 256, 0, stream>>>(
        qkv, acc, out);
}

// Round 2
// 581.204 us; speedup vs baseline: 2.4987x; 2.4987x over previous
//
#include <hip/hip_runtime.h>

#define HW      16384
#define C_DIM   256
#define S_DIM   256
#define T_K     128
#define NH      8
#define DH      32
#define QKV_ST  768
#define B_DIM   2
#define SCALE_F 0.17677669529663687f

typedef __attribute__((ext_vector_type(8))) short short8;
typedef __attribute__((ext_vector_type(4))) float f32x4;

// round-to-nearest-even float -> bf16 (as short)
__device__ __forceinline__ short f2bf(float f) {
    unsigned u = __float_as_uint(f);
    unsigned r = (u + 0x7FFFu + ((u >> 16) & 1u)) >> 16;
    return (short)r;
}

// sortable key: larger key <=> larger float (no NaNs in inputs)
__device__ __forceinline__ unsigned sortkey(float f) {
    unsigned u = __float_as_uint(f);
    return (u & 0x80000000u) ? ~u : (u | 0x80000000u);
}

// ---------------------------------------------------------------------------
// Kernel 1: per-pixel LayerNorm statistics (mean, rsqrt(var+eps)) over C
__global__ void ln_stats_kernel(const float* __restrict__ x,
                                float* __restrict__ mu,
                                float* __restrict__ rsig) {
    int p = blockIdx.x * blockDim.x + threadIdx.x;   // 0 .. B*HW-1
    int b = p >> 14;
    int n = p & (HW - 1);
    const float* xb = x + (size_t)b * C_DIM * HW + n;
    float s = 0.f, ss = 0.f;
#pragma unroll 8
    for (int c = 0; c < C_DIM; c++) {
        float v = xb[(size_t)c * HW];
        s += v; ss += v * v;
    }
    float m   = s * (1.f / C_DIM);
    float var = fmaxf(ss * (1.f / C_DIM) - m * m, 0.f);
    mu[p]   = m;
    rsig[p] = rsqrtf(var + 1e-5f);
}

// ---------------------------------------------------------------------------
// Kernel 2: fused LN + QKV projection -> qkv (B, HW, 768)
__launch_bounds__(256)
__global__ void qkv_gemm_kernel(const float* __restrict__ x,
                                const float* __restrict__ wq,
                                const float* __restrict__ wk,
                                const float* __restrict__ wv,
                                const float* __restrict__ g,
                                const float* __restrict__ beta,
                                const float* __restrict__ mu,
                                const float* __restrict__ rsig,
                                float* __restrict__ qkv) {
    int b  = blockIdx.z;
    int n0 = blockIdx.x * 64;
    int o0 = blockIdx.y * 64;
    int tid = threadIdx.x;
    int tx = tid & 15;    // o micro-index
    int ty = tid >> 4;    // n micro-index

    __shared__ float Xs[16][64];   // [c][n]
    __shared__ float Os[16][68];   // [c][o], padded

    const float* xb = x + (size_t)b * C_DIM * HW;
    float acc[4][4];
#pragma unroll
    for (int j = 0; j < 4; j++)
#pragma unroll
        for (int i = 0; i < 4; i++) acc[j][i] = 0.f;

    int nl_stage = tid & 63;
    int n_stage  = n0 + nl_stage;
    float m_st = mu[b * HW + n_stage];
    float r_st = rsig[b * HW + n_stage];

    for (int c0 = 0; c0 < C_DIM; c0 += 16) {
        {
            int ol = tid >> 2;
            int cc = (tid & 3) * 4;
            int o  = o0 + ol;
            const float* wrow;
            if (o < 256)       wrow = wq + (size_t)o * 256;
            else if (o < 512)  wrow = wk + (size_t)(o - 256) * 256;
            else               wrow = wv + (size_t)(o - 512) * 256;
            float4 w4 = *(const float4*)(wrow + c0 + cc);
            Os[cc + 0][ol] = w4.x;
            Os[cc + 1][ol] = w4.y;
            Os[cc + 2][ol] = w4.z;
            Os[cc + 3][ol] = w4.w;
        }
        {
            int crow = tid >> 6;   // 0..3
#pragma unroll
            for (int i = 0; i < 4; i++) {
                int cl = crow + i * 4;
                int c  = c0 + cl;
                float xv = xb[(size_t)c * HW + n_stage];
                Xs[cl][nl_stage] = (xv - m_st) * r_st * g[c] + beta[c];
            }
        }
        __syncthreads();
#pragma unroll
        for (int c = 0; c < 16; c++) {
            float ov[4], xv[4];
#pragma unroll
            for (int i = 0; i < 4; i++) ov[i] = Os[c][tx + 16 * i];
#pragma unroll
            for (int j = 0; j < 4; j++) xv[j] = Xs[c][ty + 16 * j];
#pragma unroll
            for (int j = 0; j < 4; j++)
#pragma unroll
                for (int i = 0; i < 4; i++) acc[j][i] += xv[j] * ov[i];
        }
        __syncthreads();
    }

    float* outb = qkv + (size_t)b * HW * QKV_ST;
#pragma unroll
    for (int j = 0; j < 4; j++) {
        size_t row = (size_t)(n0 + ty + 16 * j) * QKV_ST + o0;
#pragma unroll
        for (int i = 0; i < 4; i++) outb[row + tx + 16 * i] = acc[j][i];
    }
}

// ---------------------------------------------------------------------------
// Kernel 3: exact top-128 per (b,s) row via MSB-first radix select.
__launch_bounds__(256)
__global__ void topk_kernel(const float* __restrict__ aff,
                            float* __restrict__ sims,
                            int* __restrict__ idx) {
    int s = blockIdx.x, b = blockIdx.y;
    int tid = threadIdx.x;
    const float* row = aff + ((size_t)b * S_DIM + s) * HW;

    __shared__ unsigned hist[256];
    __shared__ unsigned s_sel, s_above;
    __shared__ int cHi, cEq;

    unsigned prefix = 0;
    int kneed = T_K;

    for (int shift = 24; shift >= 0; shift -= 8) {
        hist[tid] = 0;
        __syncthreads();
        unsigned mask = (shift == 24) ? 0u : (0xFFFFFFFFu << (shift + 8));
        for (int n = tid; n < HW; n += 256) {
            unsigned u = sortkey(row[n]);
            if ((u & mask) == prefix)
                atomicAdd(&hist[(u >> shift) & 255], 1u);
        }
        __syncthreads();
        if (tid == 0) {
            unsigned cum = 0;
            for (int bin = 255; bin >= 0; --bin) {
                unsigned c = hist[bin];
                if (cum + c >= (unsigned)kneed) { s_sel = (unsigned)bin; s_above = cum; break; }
                cum += c;
            }
        }
        __syncthreads();
        prefix |= (s_sel << shift);
        kneed  -= (int)s_above;
        __syncthreads();
    }

    unsigned T = prefix;          // 128th-largest key
    int nGt = T_K - kneed;        // count strictly greater
    if (tid == 0) { cHi = 0; cEq = 0; }
    __syncthreads();

    float* so = sims + ((size_t)b * S_DIM + s) * T_K;
    int*   io = idx  + ((size_t)b * S_DIM + s) * T_K;
    for (int n = tid; n < HW; n += 256) {
        float v = row[n];
        unsigned u = sortkey(v);
        if (u > T) {
            int p = atomicAdd(&cHi, 1);
            so[p] = v; io[p] = n;
        } else if (u == T) {
            int p = atomicAdd(&cEq, 1);
            if (p < kneed) { so[nGt + p] = v; io[nGt + p] = n; }
        }
    }
}

// ---------------------------------------------------------------------------
// Kernel 4: MFMA attention per (b, s, h). 256 threads = 4 waves.
// Wave w owns query rows t in [w*32, w*32+32), as 2 m-tiles of 16.
// QK^T: 16x16x32 MFMA (K=DH=32 in one instruction). Full-row softmax in
// C-layout registers. P -> LDS -> A-layout round trip. PV: 16 MFMAs vs
// transposed sims-weighted V. Output scaled by sims_t/l, atomicAdd into acc.
#define K_STRIDE 40    // shorts per K row (padded, 80B = 16B-aligned rows)
#define VT_STRIDE 136  // shorts per Vt row (padded, 272B = 16B-aligned rows)
__launch_bounds__(256)
__global__ void attn_kernel(const float* __restrict__ qkv,
                            const float* __restrict__ sims,
                            const int* __restrict__ idx,
                            float* __restrict__ acc) {
    int s = blockIdx.x, h = blockIdx.y, b = blockIdx.z;
    int tid  = threadIdx.x;
    int wv   = tid >> 6;
    int lane = tid & 63;
    int quad = lane >> 4;
    int ln   = lane & 15;

    __shared__ __align__(16) short K_lds[T_K * K_STRIDE];     // [u][c]
    __shared__ __align__(16) short Vt[DH * VT_STRIDE];        // [c][u], *sims[u]
    __shared__ __align__(16) short Ps[4][16 * VT_STRIDE];     // per-wave P m-tile
    __shared__ float sim_s[T_K];
    __shared__ int   idx_s[T_K];

    if (tid < T_K) {
        sim_s[tid] = sims[((size_t)b * S_DIM + s) * T_K + tid];
        idx_s[tid] = idx [((size_t)b * S_DIM + s) * T_K + tid];
    }
    __syncthreads();

    const float* qkvb = qkv + (size_t)b * HW * QKV_ST;
    int co = h * DH;

    // ---- stage K (bf16) and transposed sims-weighted V (bf16) ----
    {
        int r  = tid >> 1;
        int hh = tid & 1;
        const float* base = qkvb + (size_t)idx_s[r] * QKV_ST + co + hh * 16;
        float sm = sim_s[r];
        // K row half: 16 floats -> 16 bf16
        float4 k0 = *(const float4*)(base + 256);
        float4 k1 = *(const float4*)(base + 256 + 4);
        float4 k2 = *(const float4*)(base + 256 + 8);
        float4 k3 = *(const float4*)(base + 256 + 12);
        short8 ka, kb;
        ka[0]=f2bf(k0.x); ka[1]=f2bf(k0.y); ka[2]=f2bf(k0.z); ka[3]=f2bf(k0.w);
        ka[4]=f2bf(k1.x); ka[5]=f2bf(k1.y); ka[6]=f2bf(k1.z); ka[7]=f2bf(k1.w);
        kb[0]=f2bf(k2.x); kb[1]=f2bf(k2.y); kb[2]=f2bf(k2.z); kb[3]=f2bf(k2.w);
        kb[4]=f2bf(k3.x); kb[5]=f2bf(k3.y); kb[6]=f2bf(k3.z); kb[7]=f2bf(k3.w);
        *(short8*)&K_lds[r * K_STRIDE + hh * 16]     = ka;
        *(short8*)&K_lds[r * K_STRIDE + hh * 16 + 8] = kb;
        // V row half, weighted, scattered into transposed layout
        float4 v0 = *(const float4*)(base + 512);
        float4 v1 = *(const float4*)(base + 512 + 4);
        float4 v2 = *(const float4*)(base + 512 + 8);
        float4 v3 = *(const float4*)(base + 512 + 12);
        float vf[16] = {v0.x,v0.y,v0.z,v0.w, v1.x,v1.y,v1.z,v1.w,
                        v2.x,v2.y,v2.z,v2.w, v3.x,v3.y,v3.z,v3.w};
#pragma unroll
        for (int i = 0; i < 16; i++)
            Vt[(hh * 16 + i) * VT_STRIDE + r] = f2bf(vf[i] * sm);
    }

    // ---- this wave's Q A-fragments (scale folded in), direct from global ----
    short8 aq[2];
#pragma unroll
    for (int mt = 0; mt < 2; mt++) {
        int t = wv * 32 + mt * 16 + ln;
        const float* qb = qkvb + (size_t)idx_s[t] * QKV_ST + co + quad * 8;
        float4 a0 = *(const float4*)(qb);
        float4 a1 = *(const float4*)(qb + 4);
        aq[mt][0]=f2bf(a0.x*SCALE_F); aq[mt][1]=f2bf(a0.y*SCALE_F);
        aq[mt][2]=f2bf(a0.z*SCALE_F); aq[mt][3]=f2bf(a0.w*SCALE_F);
        aq[mt][4]=f2bf(a1.x*SCALE_F); aq[mt][5]=f2bf(a1.y*SCALE_F);
        aq[mt][6]=f2bf(a1.z*SCALE_F); aq[mt][7]=f2bf(a1.w*SCALE_F);
    }
    __syncthreads();

    // ---- QK^T: S[mt][nt] C-tiles (row=quad*4+r -> t, col=ln -> u) ----
    f32x4 S[2][8];
    const f32x4 zero4 = {0.f, 0.f, 0.f, 0.f};
#pragma unroll
    for (int nt = 0; nt < 8; nt++) {
        short8 kf = *(const short8*)&K_lds[(nt * 16 + ln) * K_STRIDE + quad * 8];
        S[0][nt] = __builtin_amdgcn_mfma_f32_16x16x32_bf16(aq[0], kf, zero4, 0, 0, 0);
        S[1][nt] = __builtin_amdgcn_mfma_f32_16x16x32_bf16(aq[1], kf, zero4, 0, 0, 0);
    }

    // ---- row softmax (max-subtracted), l per row kept in-lane ----
    float lrow[2][4];
#pragma unroll
    for (int mt = 0; mt < 2; mt++) {
#pragma unroll
        for (int r = 0; r < 4; r++) {
            float mx = S[mt][0][r];
#pragma unroll
            for (int nt = 1; nt < 8; nt++) mx = fmaxf(mx, S[mt][nt][r]);
            mx = fmaxf(mx, __shfl_xor(mx, 1, 64));
            mx = fmaxf(mx, __shfl_xor(mx, 2, 64));
            mx = fmaxf(mx, __shfl_xor(mx, 4, 64));
            mx = fmaxf(mx, __shfl_xor(mx, 8, 64));
            float l = 0.f;
#pragma unroll
            for (int nt = 0; nt < 8; nt++) {
                float p = __expf(S[mt][nt][r] - mx);
                S[mt][nt][r] = p;
                l += p;
            }
            l += __shfl_xor(l, 1, 64);
            l += __shfl_xor(l, 2, 64);
            l += __shfl_xor(l, 4, 64);
            l += __shfl_xor(l, 8, 64);
            lrow[mt][r] = l;
        }
    }

    // ---- PV with P->LDS A-layout round trip, then scatter-add ----
    float* accb = acc + (size_t)b * HW * C_DIM + co;
#pragma unroll
    for (int mt = 0; mt < 2; mt++) {
        __syncthreads();   // P buffer reuse barrier (uniform across waves)
#pragma unroll
        for (int nt = 0; nt < 8; nt++)
#pragma unroll
            for (int r = 0; r < 4; r++)
                Ps[wv][(quad * 4 + r) * VT_STRIDE + nt * 16 + ln] = f2bf(S[mt][nt][r]);
        __syncthreads();

        f32x4 O[2] = {zero4, zero4};
#pragma unroll
        for (int kt = 0; kt < 4; kt++) {
            short8 pa = *(const short8*)&Ps[wv][ln * VT_STRIDE + kt * 32 + quad * 8];
#pragma unroll
            for (int nt2 = 0; nt2 < 2; nt2++) {
                short8 vb = *(const short8*)&Vt[(nt2 * 16 + ln) * VT_STRIDE + kt * 32 + quad * 8];
                O[nt2] = __builtin_amdgcn_mfma_f32_16x16x32_bf16(pa, vb, O[nt2], 0, 0, 0);
            }
        }
#pragma unroll
        for (int nt2 = 0; nt2 < 2; nt2++)
#pragma unroll
            for (int r = 0; r < 4; r++) {
                int t = wv * 32 + mt * 16 + quad * 4 + r;
                float val = O[nt2][r] * sim_s[t] / lrow[mt][r];
                atomicAdd(accb + (size_t)idx_s[t] * C_DIM + nt2 * 16 + ln, val);
            }
    }
}

// ---------------------------------------------------------------------------
// Kernel 5: out[b][c][n] = v[b][n][c] + acc[b][n][c]  (transpose via LDS tile)
__launch_bounds__(256)
__global__ void transpose_add_kernel(const float* __restrict__ qkv,
                                     const float* __restrict__ acc,
                                     float* __restrict__ out) {
    int b  = blockIdx.z;
    int n0 = blockIdx.x * 32;
    int c0 = blockIdx.y * 32;
    int x = threadIdx.x & 31;
    int y = threadIdx.x >> 5;   // 0..7

    __shared__ float t[32][33];
#pragma unroll
    for (int r = 0; r < 4; r++) {
        int n = n0 + y + 8 * r;
        size_t row = (size_t)b * HW + n;
        t[y + 8 * r][x] = qkv[row * QKV_ST + 512 + c0 + x] + acc[row * C_DIM + c0 + x];
    }
    __syncthreads();
#pragma unroll
    for (int r = 0; r < 4; r++) {
        int c = c0 + y + 8 * r;
        out[((size_t)b * C_DIM + c) * HW + n0 + x] = t[x][y + 8 * r];
    }
}

// ---------------------------------------------------------------------------
extern "C" void kernel_launch(void* const* d_in, const int* in_sizes, int n_in,
                              void* d_out, int out_size, void* d_ws, size_t ws_size,
                              hipStream_t stream) {
    const float* x    = (const float*)d_in[0];
    const float* aff  = (const float*)d_in[1];
    const float* g    = (const float*)d_in[2];
    const float* beta = (const float*)d_in[3];
    const float* wq   = (const float*)d_in[4];
    const float* wk   = (const float*)d_in[5];
    const float* wv   = (const float*)d_in[6];
    float* out = (float*)d_out;

    float* ws   = (float*)d_ws;
    float* qkv  = ws;                                         // B*HW*768
    float* mu   = qkv  + (size_t)B_DIM * HW * QKV_ST;         // B*HW
    float* rsig = mu   + (size_t)B_DIM * HW;                  // B*HW
    float* simsb= rsig + (size_t)B_DIM * HW;                  // B*S*T
    float* acc  = simsb+ (size_t)B_DIM * S_DIM * T_K;         // B*HW*C
    int*   idxb = (int*)(acc + (size_t)B_DIM * HW * C_DIM);   // B*S*T ints

    hipMemsetAsync(acc, 0, (size_t)B_DIM * HW * C_DIM * sizeof(float), stream);

    ln_stats_kernel<<<dim3(B_DIM * HW / 256), 256, 0, stream>>>(x, mu, rsig);
    qkv_gemm_kernel<<<dim3(HW / 64, QKV_ST / 64, B_DIM), 256, 0, stream>>>(
        x, wq, wk, wv, g, beta, mu, rsig, qkv);
    topk_kernel<<<dim3(S_DIM, B_DIM), 256, 0, stream>>>(aff, simsb, idxb);
    attn_kernel<<<dim3(S_DIM, NH, B_DIM), 256, 0, stream>>>(qkv, simsb, idxb, acc);
    transpose_add_kernel<<<dim3(HW / 32, C_DIM / 32, B_DIM), 256, 0, stream>>>(
        qkv, acc, out);
}

// Round 3
// 409.653 us; speedup vs baseline: 3.5451x; 1.4188x over previous
//
#include <hip/hip_runtime.h>

#define HW      16384
#define C_DIM   256
#define S_DIM   256
#define T_K     128
#define NH      8
#define DH      32
#define QKV_ST  768
#define B_DIM   2
#define SCALE_F 0.17677669529663687f

typedef __attribute__((ext_vector_type(8))) short short8;
typedef __attribute__((ext_vector_type(4))) float f32x4;

// round-to-nearest-even float -> bf16 (as short)
__device__ __forceinline__ short f2bf(float f) {
    unsigned u = __float_as_uint(f);
    unsigned r = (u + 0x7FFFu + ((u >> 16) & 1u)) >> 16;
    return (short)r;
}
__device__ __forceinline__ float bf2f(short s) {
    unsigned u = ((unsigned)(unsigned short)s) << 16;
    return __uint_as_float(u);
}

// sortable key: larger key <=> larger float (no NaNs in inputs)
__device__ __forceinline__ unsigned sortkey(float f) {
    unsigned u = __float_as_uint(f);
    return (u & 0x80000000u) ? ~u : (u | 0x80000000u);
}

// ---------------------------------------------------------------------------
// Kernel 1: per-pixel LayerNorm statistics (mean, rsqrt(var+eps)) over C
__global__ void ln_stats_kernel(const float* __restrict__ x,
                                float* __restrict__ mu,
                                float* __restrict__ rsig) {
    int p = blockIdx.x * blockDim.x + threadIdx.x;   // 0 .. B*HW-1
    int b = p >> 14;
    int n = p & (HW - 1);
    const float* xb = x + (size_t)b * C_DIM * HW + n;
    float s = 0.f, ss = 0.f;
#pragma unroll 8
    for (int c = 0; c < C_DIM; c++) {
        float v = xb[(size_t)c * HW];
        s += v; ss += v * v;
    }
    float m   = s * (1.f / C_DIM);
    float var = fmaxf(ss * (1.f / C_DIM) - m * m, 0.f);
    mu[p]   = m;
    rsig[p] = rsqrtf(var + 1e-5f);
}

// ---------------------------------------------------------------------------
// Kernel 1b: pack weights to bf16, layout Wb[o][c] (o: 0..255 q, 256..511 k, 512..767 v)
__global__ void wpack_kernel(const float* __restrict__ wq,
                             const float* __restrict__ wk,
                             const float* __restrict__ wv,
                             short* __restrict__ wb) {
    int gid  = blockIdx.x * 256 + threadIdx.x;   // 49152 threads, 4 elems each
    int base = gid * 4;
    int o = base >> 8;
    int c = base & 255;
    const float* src = (o < 256) ? wq + (size_t)o * 256
                     : (o < 512) ? wk + (size_t)(o - 256) * 256
                                 : wv + (size_t)(o - 512) * 256;
    float4 w4 = *(const float4*)(src + c);
    short4 s4;
    s4.x = f2bf(w4.x); s4.y = f2bf(w4.y); s4.z = f2bf(w4.z); s4.w = f2bf(w4.w);
    *(short4*)&wb[base] = s4;
}

// ---------------------------------------------------------------------------
// Kernel 1c: LN-apply + transpose: xnT[b][n][c] = bf16(LN(x[b][c][n]))
__launch_bounds__(256)
__global__ void xpack_kernel(const float* __restrict__ x,
                             const float* __restrict__ g,
                             const float* __restrict__ beta,
                             const float* __restrict__ mu,
                             const float* __restrict__ rsig,
                             short* __restrict__ xnT) {
    int b  = blockIdx.z;
    int n0 = blockIdx.x * 64;
    int c0 = blockIdx.y * 64;
    int tid = threadIdx.x;

    __shared__ float t[64][65];

    // read 64c x 64n tile, coalesced rows
    {
        int cl = tid >> 2;
        int ni = (tid & 3) * 16;
        const float* src = x + ((size_t)b * C_DIM + c0 + cl) * HW + n0 + ni;
#pragma unroll
        for (int j = 0; j < 4; j++) {
            float4 v = *(const float4*)(src + j * 4);
            t[cl][ni + j * 4 + 0] = v.x;
            t[cl][ni + j * 4 + 1] = v.y;
            t[cl][ni + j * 4 + 2] = v.z;
            t[cl][ni + j * 4 + 3] = v.w;
        }
    }
    __syncthreads();

    // write transposed with LN applied
    {
        int nl = tid >> 2;
        int ci = (tid & 3) * 16;
        int n  = n0 + nl;
        float m  = mu[b * HW + n];
        float rs = rsig[b * HW + n];
        short8 s0, s1;
#pragma unroll
        for (int j = 0; j < 8; j++) {
            int c = c0 + ci + j;
            s0[j] = f2bf((t[ci + j][nl] - m) * rs * g[c] + beta[c]);
        }
#pragma unroll
        for (int j = 0; j < 8; j++) {
            int c = c0 + ci + 8 + j;
            s1[j] = f2bf((t[ci + 8 + j][nl] - m) * rs * g[c] + beta[c]);
        }
        short* dst = xnT + ((size_t)b * HW + n) * C_DIM + c0 + ci;
        *(short8*)(dst)     = s0;
        *(short8*)(dst + 8) = s1;
    }
}

// ---------------------------------------------------------------------------
// Kernel 2: bf16 MFMA QKV projection. qkv[b][n][o] (bf16), 128n x 128o tiles,
// 4 waves in 2x2, each wave 64x64 via 4x4 MFMA 16x16x32 tiles.
// A/B fragments are direct global b128 loads (xnT/Wb are k-contiguous).
#define E_STRIDE 136
__launch_bounds__(256)
__global__ void qkv_mfma_kernel(const short* __restrict__ xnT,
                                const short* __restrict__ wb,
                                short* __restrict__ qkv) {
    int b  = blockIdx.z;
    int n0 = blockIdx.x * 128;
    int o0 = blockIdx.y * 128;
    int tid  = threadIdx.x;
    int wv   = tid >> 6;
    int wn   = wv & 1;
    int wo   = wv >> 1;
    int lane = tid & 63;
    int quad = lane >> 4;
    int ln   = lane & 15;

    __shared__ __align__(16) short Es[128 * E_STRIDE];

    const short* arow[4];
    const short* brow[4];
#pragma unroll
    for (int mt = 0; mt < 4; mt++)
        arow[mt] = xnT + ((size_t)b * HW + n0 + wn * 64 + mt * 16 + ln) * C_DIM + quad * 8;
#pragma unroll
    for (int nt = 0; nt < 4; nt++)
        brow[nt] = wb + (size_t)(o0 + wo * 64 + nt * 16 + ln) * C_DIM + quad * 8;

    f32x4 acc[4][4];
    const f32x4 zero4 = {0.f, 0.f, 0.f, 0.f};
#pragma unroll
    for (int mt = 0; mt < 4; mt++)
#pragma unroll
        for (int nt = 0; nt < 4; nt++) acc[mt][nt] = zero4;

#pragma unroll 2
    for (int c0 = 0; c0 < C_DIM; c0 += 32) {
        short8 af[4], bf[4];
#pragma unroll
        for (int mt = 0; mt < 4; mt++) af[mt] = *(const short8*)(arow[mt] + c0);
#pragma unroll
        for (int nt = 0; nt < 4; nt++) bf[nt] = *(const short8*)(brow[nt] + c0);
#pragma unroll
        for (int mt = 0; mt < 4; mt++)
#pragma unroll
            for (int nt = 0; nt < 4; nt++)
                acc[mt][nt] = __builtin_amdgcn_mfma_f32_16x16x32_bf16(af[mt], bf[nt], acc[mt][nt], 0, 0, 0);
    }

    // epilogue: C-layout -> LDS -> coalesced bf16 stores
#pragma unroll
    for (int mt = 0; mt < 4; mt++)
#pragma unroll
        for (int nt = 0; nt < 4; nt++)
#pragma unroll
            for (int r = 0; r < 4; r++)
                Es[(wn * 64 + mt * 16 + quad * 4 + r) * E_STRIDE + wo * 64 + nt * 16 + ln] =
                    f2bf(acc[mt][nt][r]);
    __syncthreads();

    {
        int nl   = tid >> 1;
        int half = tid & 1;
        const short* srcr = &Es[nl * E_STRIDE + half * 64];
        short* dst = qkv + ((size_t)b * HW + n0 + nl) * QKV_ST + o0 + half * 64;
#pragma unroll
        for (int j = 0; j < 8; j++)
            *(short8*)(dst + j * 8) = *(const short8*)(srcr + j * 8);
    }
}

// ---------------------------------------------------------------------------
// Kernel 3: exact top-128 per (b,s) row via MSB-first radix select.
__launch_bounds__(256)
__global__ void topk_kernel(const float* __restrict__ aff,
                            float* __restrict__ sims,
                            int* __restrict__ idx) {
    int s = blockIdx.x, b = blockIdx.y;
    int tid = threadIdx.x;
    const float* row = aff + ((size_t)b * S_DIM + s) * HW;

    __shared__ unsigned hist[256];
    __shared__ unsigned s_sel, s_above;
    __shared__ int cHi, cEq;

    unsigned prefix = 0;
    int kneed = T_K;

    for (int shift = 24; shift >= 0; shift -= 8) {
        hist[tid] = 0;
        __syncthreads();
        unsigned mask = (shift == 24) ? 0u : (0xFFFFFFFFu << (shift + 8));
        for (int n = tid; n < HW; n += 256) {
            unsigned u = sortkey(row[n]);
            if ((u & mask) == prefix)
                atomicAdd(&hist[(u >> shift) & 255], 1u);
        }
        __syncthreads();
        if (tid == 0) {
            unsigned cum = 0;
            for (int bin = 255; bin >= 0; --bin) {
                unsigned c = hist[bin];
                if (cum + c >= (unsigned)kneed) { s_sel = (unsigned)bin; s_above = cum; break; }
                cum += c;
            }
        }
        __syncthreads();
        prefix |= (s_sel << shift);
        kneed  -= (int)s_above;
        __syncthreads();
    }

    unsigned T = prefix;          // 128th-largest key
    int nGt = T_K - kneed;        // count strictly greater
    if (tid == 0) { cHi = 0; cEq = 0; }
    __syncthreads();

    float* so = sims + ((size_t)b * S_DIM + s) * T_K;
    int*   io = idx  + ((size_t)b * S_DIM + s) * T_K;
    for (int n = tid; n < HW; n += 256) {
        float v = row[n];
        unsigned u = sortkey(v);
        if (u > T) {
            int p = atomicAdd(&cHi, 1);
            so[p] = v; io[p] = n;
        } else if (u == T) {
            int p = atomicAdd(&cEq, 1);
            if (p < kneed) { so[nGt + p] = v; io[nGt + p] = n; }
        }
    }
}

// ---------------------------------------------------------------------------
// Kernel 4: MFMA attention per (b, s, h); qkv is bf16. sims folded into P.
#define K_STRIDE 40    // shorts per K row
#define VT_STRIDE 136  // shorts per Vt/Ps row
__launch_bounds__(256)
__global__ void attn_kernel(const short* __restrict__ qkv,
                            const float* __restrict__ sims,
                            const int* __restrict__ idx,
                            float* __restrict__ acc) {
    int s = blockIdx.x, h = blockIdx.y, b = blockIdx.z;
    int tid  = threadIdx.x;
    int wv   = tid >> 6;
    int lane = tid & 63;
    int quad = lane >> 4;
    int ln   = lane & 15;

    __shared__ __align__(16) short K_lds[T_K * K_STRIDE];     // [u][c]
    __shared__ __align__(16) short Vt[DH * VT_STRIDE];        // [c][u]
    __shared__ __align__(16) short Ps[4][16 * VT_STRIDE];     // per-wave P m-tile
    __shared__ float sim_s[T_K];
    __shared__ int   idx_s[T_K];

    if (tid < T_K) {
        sim_s[tid] = sims[((size_t)b * S_DIM + s) * T_K + tid];
        idx_s[tid] = idx [((size_t)b * S_DIM + s) * T_K + tid];
    }
    __syncthreads();

    const short* qkvb = qkv + (size_t)b * HW * QKV_ST;
    int co = h * DH;

    // ---- stage K and transposed V (both bf16 copies) ----
    {
        int r  = tid >> 1;
        int hh = tid & 1;
        const short* base = qkvb + (size_t)idx_s[r] * QKV_ST + co + hh * 16;
        short8 k0 = *(const short8*)(base + 256);
        short8 k1 = *(const short8*)(base + 256 + 8);
        *(short8*)&K_lds[r * K_STRIDE + hh * 16]     = k0;
        *(short8*)&K_lds[r * K_STRIDE + hh * 16 + 8] = k1;
        short8 v0 = *(const short8*)(base + 512);
        short8 v1 = *(const short8*)(base + 512 + 8);
#pragma unroll
        for (int i = 0; i < 8; i++) Vt[(hh * 16 + i) * VT_STRIDE + r]     = v0[i];
#pragma unroll
        for (int i = 0; i < 8; i++) Vt[(hh * 16 + 8 + i) * VT_STRIDE + r] = v1[i];
    }

    // ---- this wave's Q A-fragments, direct bf16 gather ----
    short8 aq[2];
#pragma unroll
    for (int mt = 0; mt < 2; mt++) {
        int t = wv * 32 + mt * 16 + ln;
        aq[mt] = *(const short8*)(qkvb + (size_t)idx_s[t] * QKV_ST + co + quad * 8);
    }
    __syncthreads();

    // ---- QK^T ----
    f32x4 S[2][8];
    const f32x4 zero4 = {0.f, 0.f, 0.f, 0.f};
#pragma unroll
    for (int nt = 0; nt < 8; nt++) {
        short8 kf = *(const short8*)&K_lds[(nt * 16 + ln) * K_STRIDE + quad * 8];
        S[0][nt] = __builtin_amdgcn_mfma_f32_16x16x32_bf16(aq[0], kf, zero4, 0, 0, 0);
        S[1][nt] = __builtin_amdgcn_mfma_f32_16x16x32_bf16(aq[1], kf, zero4, 0, 0, 0);
    }

    // ---- row softmax (scale applied here) ----
    float lrow[2][4];
#pragma unroll
    for (int mt = 0; mt < 2; mt++) {
#pragma unroll
        for (int r = 0; r < 4; r++) {
            float mx = S[mt][0][r];
#pragma unroll
            for (int nt = 1; nt < 8; nt++) mx = fmaxf(mx, S[mt][nt][r]);
            mx = fmaxf(mx, __shfl_xor(mx, 1, 64));
            mx = fmaxf(mx, __shfl_xor(mx, 2, 64));
            mx = fmaxf(mx, __shfl_xor(mx, 4, 64));
            mx = fmaxf(mx, __shfl_xor(mx, 8, 64));
            float l = 0.f;
#pragma unroll
            for (int nt = 0; nt < 8; nt++) {
                float p = __expf((S[mt][nt][r] - mx) * SCALE_F);
                S[mt][nt][r] = p;
                l += p;
            }
            l += __shfl_xor(l, 1, 64);
            l += __shfl_xor(l, 2, 64);
            l += __shfl_xor(l, 4, 64);
            l += __shfl_xor(l, 8, 64);
            lrow[mt][r] = l;
        }
    }

    // ---- PV (P weighted by sims_u) + scatter-add ----
    float* accb = acc + (size_t)b * HW * C_DIM + co;
#pragma unroll
    for (int mt = 0; mt < 2; mt++) {
        __syncthreads();
#pragma unroll
        for (int nt = 0; nt < 8; nt++) {
            float su = sim_s[nt * 16 + ln];
#pragma unroll
            for (int r = 0; r < 4; r++)
                Ps[wv][(quad * 4 + r) * VT_STRIDE + nt * 16 + ln] = f2bf(S[mt][nt][r] * su);
        }
        __syncthreads();

        f32x4 O[2] = {zero4, zero4};
#pragma unroll
        for (int kt = 0; kt < 4; kt++) {
            short8 pa = *(const short8*)&Ps[wv][ln * VT_STRIDE + kt * 32 + quad * 8];
#pragma unroll
            for (int nt2 = 0; nt2 < 2; nt2++) {
                short8 vb = *(const short8*)&Vt[(nt2 * 16 + ln) * VT_STRIDE + kt * 32 + quad * 8];
                O[nt2] = __builtin_amdgcn_mfma_f32_16x16x32_bf16(pa, vb, O[nt2], 0, 0, 0);
            }
        }
#pragma unroll
        for (int nt2 = 0; nt2 < 2; nt2++)
#pragma unroll
            for (int r = 0; r < 4; r++) {
                int t = wv * 32 + mt * 16 + quad * 4 + r;
                float val = O[nt2][r] * sim_s[t] / lrow[mt][r];
                atomicAdd(accb + (size_t)idx_s[t] * C_DIM + nt2 * 16 + ln, val);
            }
    }
}

// ---------------------------------------------------------------------------
// Kernel 5: out[b][c][n] = bf2f(v[b][n][c]) + acc[b][n][c]
__launch_bounds__(256)
__global__ void transpose_add_kernel(const short* __restrict__ qkv,
                                     const float* __restrict__ acc,
                                     float* __restrict__ out) {
    int b  = blockIdx.z;
    int n0 = blockIdx.x * 32;
    int c0 = blockIdx.y * 32;
    int x = threadIdx.x & 31;
    int y = threadIdx.x >> 5;   // 0..7

    __shared__ float t[32][33];
#pragma unroll
    for (int r = 0; r < 4; r++) {
        int n = n0 + y + 8 * r;
        size_t row = (size_t)b * HW + n;
        t[y + 8 * r][x] = bf2f(qkv[row * QKV_ST + 512 + c0 + x]) + acc[row * C_DIM + c0 + x];
    }
    __syncthreads();
#pragma unroll
    for (int r = 0; r < 4; r++) {
        int c = c0 + y + 8 * r;
        out[((size_t)b * C_DIM + c) * HW + n0 + x] = t[x][y + 8 * r];
    }
}

// ---------------------------------------------------------------------------
extern "C" void kernel_launch(void* const* d_in, const int* in_sizes, int n_in,
                              void* d_out, int out_size, void* d_ws, size_t ws_size,
                              hipStream_t stream) {
    const float* x    = (const float*)d_in[0];
    const float* aff  = (const float*)d_in[1];
    const float* g    = (const float*)d_in[2];
    const float* beta = (const float*)d_in[3];
    const float* wq   = (const float*)d_in[4];
    const float* wk   = (const float*)d_in[5];
    const float* wv   = (const float*)d_in[6];
    float* out = (float*)d_out;

    char* ws = (char*)d_ws;
    short* qkv  = (short*)ws;                                   ws += (size_t)B_DIM * HW * QKV_ST * 2;
    short* xnT  = (short*)ws;                                   ws += (size_t)B_DIM * HW * C_DIM * 2;
    short* wbuf = (short*)ws;                                   ws += (size_t)QKV_ST * C_DIM * 2;
    float* mu   = (float*)ws;                                   ws += (size_t)B_DIM * HW * 4;
    float* rsig = (float*)ws;                                   ws += (size_t)B_DIM * HW * 4;
    float* simsb= (float*)ws;                                   ws += (size_t)B_DIM * S_DIM * T_K * 4;
    int*   idxb = (int*)ws;                                     ws += (size_t)B_DIM * S_DIM * T_K * 4;
    float* acc  = (float*)ws;

    hipMemsetAsync(acc, 0, (size_t)B_DIM * HW * C_DIM * sizeof(float), stream);

    ln_stats_kernel<<<dim3(B_DIM * HW / 256), 256, 0, stream>>>(x, mu, rsig);
    wpack_kernel<<<dim3(QKV_ST * C_DIM / 4 / 256), 256, 0, stream>>>(wq, wk, wv, wbuf);
    xpack_kernel<<<dim3(HW / 64, C_DIM / 64, B_DIM), 256, 0, stream>>>(
        x, g, beta, mu, rsig, xnT);
    qkv_mfma_kernel<<<dim3(HW / 128, QKV_ST / 128, B_DIM), 256, 0, stream>>>(
        xnT, wbuf, qkv);
    topk_kernel<<<dim3(S_DIM, B_DIM), 256, 0, stream>>>(aff, simsb, idxb);
    attn_kernel<<<dim3(S_DIM, NH, B_DIM), 256, 0, stream>>>(qkv, simsb, idxb, acc);
    transpose_add_kernel<<<dim3(HW / 32, C_DIM / 32, B_DIM), 256, 0, stream>>>(
        qkv, acc, out);
}

// Round 6
// 349.978 us; speedup vs baseline: 4.1496x; 1.1705x over previous
//
#include <hip/hip_runtime.h>

#define HW      16384
#define C_DIM   256
#define S_DIM   256
#define T_K     128
#define NH      8
#define DH      32
#define QKV_ST  768
#define B_DIM   2
#define SCALE_F 0.17677669529663687f
#define CAND    1536
#define EQCAP   512

typedef __attribute__((ext_vector_type(8))) short short8;
typedef __attribute__((ext_vector_type(4))) float f32x4;

// round-to-nearest-even float -> bf16 (as short)
__device__ __forceinline__ short f2bf(float f) {
    unsigned u = __float_as_uint(f);
    unsigned r = (u + 0x7FFFu + ((u >> 16) & 1u)) >> 16;
    return (short)r;
}
__device__ __forceinline__ float bf2f(short s) {
    unsigned u = ((unsigned)(unsigned short)s) << 16;
    return __uint_as_float(u);
}

// sortable key: larger key <=> larger float (no NaNs in inputs)
__device__ __forceinline__ unsigned sortkey(float f) {
    unsigned u = __float_as_uint(f);
    return (u & 0x80000000u) ? ~u : (u | 0x80000000u);
}
__device__ __forceinline__ float keyval(unsigned k) {
    return __uint_as_float((k & 0x80000000u) ? (k ^ 0x80000000u) : ~k);
}

// wave-aggregated histogram add: one LDS atomic per distinct bin per wave
__device__ __forceinline__ void agg_hist_add(unsigned* hist, unsigned bin) {
    int lane = threadIdx.x & 63;
    unsigned long long rem = ~0ull;
    while (true) {
        int leader = __ffsll((unsigned long long)rem) - 1;
        unsigned lbin = __shfl(bin, leader, 64);
        unsigned long long eq = __ballot(bin == lbin);
        if (lane == leader) atomicAdd(&hist[lbin], (unsigned)__popcll(eq & rem));
        rem &= ~eq;
        if (rem == 0ull) break;
    }
}

// ---------------------------------------------------------------------------
// Kernel 1: per-pixel LayerNorm statistics (mean, rsqrt(var+eps)) over C
__global__ void ln_stats_kernel(const float* __restrict__ x,
                                float* __restrict__ mu,
                                float* __restrict__ rsig) {
    int p = blockIdx.x * blockDim.x + threadIdx.x;   // 0 .. B*HW-1
    int b = p >> 14;
    int n = p & (HW - 1);
    const float* xb = x + (size_t)b * C_DIM * HW + n;
    float s = 0.f, ss = 0.f;
#pragma unroll 8
    for (int c = 0; c < C_DIM; c++) {
        float v = xb[(size_t)c * HW];
        s += v; ss += v * v;
    }
    float m   = s * (1.f / C_DIM);
    float var = fmaxf(ss * (1.f / C_DIM) - m * m, 0.f);
    mu[p]   = m;
    rsig[p] = rsqrtf(var + 1e-5f);
}

// ---------------------------------------------------------------------------
// Kernel 1b: pack weights to bf16, layout Wb[o][c]
__global__ void wpack_kernel(const float* __restrict__ wq,
                             const float* __restrict__ wk,
                             const float* __restrict__ wv,
                             short* __restrict__ wb) {
    int gid  = blockIdx.x * 256 + threadIdx.x;
    int base = gid * 4;
    int o = base >> 8;
    int c = base & 255;
    const float* src = (o < 256) ? wq + (size_t)o * 256
                     : (o < 512) ? wk + (size_t)(o - 256) * 256
                                 : wv + (size_t)(o - 512) * 256;
    float4 w4 = *(const float4*)(src + c);
    short4 s4;
    s4.x = f2bf(w4.x); s4.y = f2bf(w4.y); s4.z = f2bf(w4.z); s4.w = f2bf(w4.w);
    *(short4*)&wb[base] = s4;
}

// ---------------------------------------------------------------------------
// Kernel 1c: LN-apply + transpose: xnT[b][n][c] = bf16(LN(x[b][c][n]))
__launch_bounds__(256)
__global__ void xpack_kernel(const float* __restrict__ x,
                             const float* __restrict__ g,
                             const float* __restrict__ beta,
                             const float* __restrict__ mu,
                             const float* __restrict__ rsig,
                             short* __restrict__ xnT) {
    int b  = blockIdx.z;
    int n0 = blockIdx.x * 64;
    int c0 = blockIdx.y * 64;
    int tid = threadIdx.x;

    __shared__ float t[64][65];

    {
        int cl = tid >> 2;
        int ni = (tid & 3) * 16;
        const float* src = x + ((size_t)b * C_DIM + c0 + cl) * HW + n0 + ni;
#pragma unroll
        for (int j = 0; j < 4; j++) {
            float4 v = *(const float4*)(src + j * 4);
            t[cl][ni + j * 4 + 0] = v.x;
            t[cl][ni + j * 4 + 1] = v.y;
            t[cl][ni + j * 4 + 2] = v.z;
            t[cl][ni + j * 4 + 3] = v.w;
        }
    }
    __syncthreads();

    {
        int nl = tid >> 2;
        int ci = (tid & 3) * 16;
        int n  = n0 + nl;
        float m  = mu[b * HW + n];
        float rs = rsig[b * HW + n];
        short8 s0, s1;
#pragma unroll
        for (int j = 0; j < 8; j++) {
            int c = c0 + ci + j;
            s0[j] = f2bf((t[ci + j][nl] - m) * rs * g[c] + beta[c]);
        }
#pragma unroll
        for (int j = 0; j < 8; j++) {
            int c = c0 + ci + 8 + j;
            s1[j] = f2bf((t[ci + 8 + j][nl] - m) * rs * g[c] + beta[c]);
        }
        short* dst = xnT + ((size_t)b * HW + n) * C_DIM + c0 + ci;
        *(short8*)(dst)     = s0;
        *(short8*)(dst + 8) = s1;
    }
}

// ---------------------------------------------------------------------------
// Kernel 2: bf16 MFMA QKV projection
#define E_STRIDE 136
__launch_bounds__(256)
__global__ void qkv_mfma_kernel(const short* __restrict__ xnT,
                                const short* __restrict__ wb,
                                short* __restrict__ qkv) {
    int b  = blockIdx.z;
    int n0 = blockIdx.x * 128;
    int o0 = blockIdx.y * 128;
    int tid  = threadIdx.x;
    int wv   = tid >> 6;
    int wn   = wv & 1;
    int wo   = wv >> 1;
    int lane = tid & 63;
    int quad = lane >> 4;
    int ln   = lane & 15;

    __shared__ __align__(16) short Es[128 * E_STRIDE];

    const short* arow[4];
    const short* brow[4];
#pragma unroll
    for (int mt = 0; mt < 4; mt++)
        arow[mt] = xnT + ((size_t)b * HW + n0 + wn * 64 + mt * 16 + ln) * C_DIM + quad * 8;
#pragma unroll
    for (int nt = 0; nt < 4; nt++)
        brow[nt] = wb + (size_t)(o0 + wo * 64 + nt * 16 + ln) * C_DIM + quad * 8;

    f32x4 acc[4][4];
    const f32x4 zero4 = {0.f, 0.f, 0.f, 0.f};
#pragma unroll
    for (int mt = 0; mt < 4; mt++)
#pragma unroll
        for (int nt = 0; nt < 4; nt++) acc[mt][nt] = zero4;

#pragma unroll 2
    for (int c0 = 0; c0 < C_DIM; c0 += 32) {
        short8 af[4], bf[4];
#pragma unroll
        for (int mt = 0; mt < 4; mt++) af[mt] = *(const short8*)(arow[mt] + c0);
#pragma unroll
        for (int nt = 0; nt < 4; nt++) bf[nt] = *(const short8*)(brow[nt] + c0);
#pragma unroll
        for (int mt = 0; mt < 4; mt++)
#pragma unroll
            for (int nt = 0; nt < 4; nt++)
                acc[mt][nt] = __builtin_amdgcn_mfma_f32_16x16x32_bf16(af[mt], bf[nt], acc[mt][nt], 0, 0, 0);
    }

#pragma unroll
    for (int mt = 0; mt < 4; mt++)
#pragma unroll
        for (int nt = 0; nt < 4; nt++)
#pragma unroll
            for (int r = 0; r < 4; r++)
                Es[(wn * 64 + mt * 16 + quad * 4 + r) * E_STRIDE + wo * 64 + nt * 16 + ln] =
                    f2bf(acc[mt][nt][r]);
    __syncthreads();

    {
        int nl   = tid >> 1;
        int half = tid & 1;
        const short* srcr = &Es[nl * E_STRIDE + half * 64];
        short* dst = qkv + ((size_t)b * HW + n0 + nl) * QKV_ST + o0 + half * 64;
#pragma unroll
        for (int j = 0; j < 8; j++)
            *(short8*)(dst + j * 8) = *(const short8*)(srcr + j * 8);
    }
}

// ---------------------------------------------------------------------------
// Kernel 3: exact top-128 per (b,s) row.
// Race-free by construction: kneed/prefix are UNIFORM REGISTERS recomputed
// identically by all threads from post-barrier shared data; the only shared
// handoff is s_sel (unique single writer, write -> barrier -> read).
// Ties at the threshold key keep the LOWEST indices (matches jax top_k).
__launch_bounds__(256)
__global__ void topk_kernel(const float* __restrict__ aff,
                            float* __restrict__ sims,
                            int* __restrict__ idx) {
    int s = blockIdx.x, b = blockIdx.y;
    int tid = threadIdx.x;
    const float4* rowv4 = (const float4*)(aff + ((size_t)b * S_DIM + s) * HW);

    __shared__ unsigned hist[256];
    __shared__ unsigned sufs[256];
    __shared__ unsigned ckey[CAND];
    __shared__ int      cidx[CAND];
    __shared__ int      eqix[EQCAP];
    __shared__ int s_sel, cHi, cCand, cEq;

    if (tid == 0) { cHi = 0; cCand = 0; cEq = 0; }
    hist[tid] = 0;
    __syncthreads();

    // ---- pass 1: MSB-byte histogram over full row (wave-aggregated) ----
    for (int i = tid; i < HW / 4; i += 256) {
        float4 v = rowv4[i];
        agg_hist_add(hist, sortkey(v.x) >> 24);
        agg_hist_add(hist, sortkey(v.y) >> 24);
        agg_hist_add(hist, sortkey(v.z) >> 24);
        agg_hist_add(hist, sortkey(v.w) >> 24);
    }
    __syncthreads();

    // ---- suffix scan ----
    sufs[tid] = hist[tid];
    __syncthreads();
#pragma unroll
    for (int off = 1; off < 256; off <<= 1) {
        unsigned v = (tid + off < 256) ? sufs[tid + off] : 0u;
        __syncthreads();
        sufs[tid] += v;
        __syncthreads();
    }

    int kneed = T_K;            // uniform register on every thread
    {
        unsigned above = (tid < 255) ? sufs[tid + 1] : 0u;
        if ((int)sufs[tid] >= kneed && (int)above < kneed) s_sel = tid;  // unique winner
        __syncthreads();
    }
    int sel = s_sel;            // uniform
    unsigned prefix = (unsigned)sel << 24;
    kneed -= (int)((sel < 255) ? sufs[sel + 1] : 0u);
    __syncthreads();

    float* so = sims + ((size_t)b * S_DIM + s) * T_K;
    int*   io = idx  + ((size_t)b * S_DIM + s) * T_K;

    // ---- pass 2: direct-emit above-bin, compact in-bin candidates ----
    for (int i = tid; i < HW / 4; i += 256) {
        float4 v = rowv4[i];
        float vf[4] = {v.x, v.y, v.z, v.w};
#pragma unroll
        for (int j = 0; j < 4; j++) {
            unsigned u  = sortkey(vf[j]);
            unsigned hb = u >> 24;
            if (hb > (unsigned)sel) {
                int p = atomicAdd(&cHi, 1);
                so[p] = vf[j]; io[p] = i * 4 + j;
            } else if (hb == (unsigned)sel) {
                int c = atomicAdd(&cCand, 1);
                if (c < CAND) { ckey[c] = u; cidx[c] = i * 4 + j; }
            }
        }
    }
    __syncthreads();
    int nc = min(cCand, CAND);

    // ---- 3 radix refinements over candidates ----
    for (int shift = 16; shift >= 0; shift -= 8) {
        hist[tid] = 0;
        __syncthreads();
        unsigned mask = 0xFFFFFFFFu << (shift + 8);
        for (int i = tid; i < nc; i += 256) {
            unsigned u = ckey[i];
            if ((u & mask) == prefix) atomicAdd(&hist[(u >> shift) & 255], 1u);
        }
        __syncthreads();
        sufs[tid] = hist[tid];
        __syncthreads();
#pragma unroll
        for (int off = 1; off < 256; off <<= 1) {
            unsigned v = (tid + off < 256) ? sufs[tid + off] : 0u;
            __syncthreads();
            sufs[tid] += v;
            __syncthreads();
        }
        {
            unsigned above = (tid < 255) ? sufs[tid + 1] : 0u;
            if ((int)sufs[tid] >= kneed && (int)above < kneed) s_sel = tid;
            __syncthreads();
        }
        sel = s_sel;
        prefix |= (unsigned)sel << shift;
        kneed  -= (int)((sel < 255) ? sufs[sel + 1] : 0u);
        __syncthreads();
    }

    unsigned T = prefix;        // exact 128th-largest key
    int kneedF = kneed;         // # of equal-to-T entries to keep (>=1)

    // ---- emit >T; compact ==T for deterministic tie resolution ----
    for (int i = tid; i < nc; i += 256) {
        unsigned u = ckey[i];
        if (u > T) {
            int p = atomicAdd(&cHi, 1);
            so[p] = keyval(u); io[p] = cidx[i];
        } else if (u == T) {
            int q = atomicAdd(&cEq, 1);
            if (q < EQCAP) eqix[q] = cidx[i];
        }
    }
    __syncthreads();
    int m = min(cEq, EQCAP);

    // keep the kneedF SMALLEST indices among equals (jax tie order)
    float tval = keyval(T);
    for (int i = tid; i < m; i += 256) {
        int my = eqix[i];
        int rank = 0;
        for (int j = 0; j < m; j++) rank += (eqix[j] < my);
        if (rank < kneedF) { so[127 - rank] = tval; io[127 - rank] = my; }
    }
}

// ---------------------------------------------------------------------------
// Kernel 4: MFMA attention per (b, s, h); qkv is bf16. sims folded into P.
#define K_STRIDE 40
#define VT_STRIDE 136
__launch_bounds__(256)
__global__ void attn_kernel(const short* __restrict__ qkv,
                            const float* __restrict__ sims,
                            const int* __restrict__ idx,
                            float* __restrict__ acc) {
    int s = blockIdx.x, h = blockIdx.y, b = blockIdx.z;
    int tid  = threadIdx.x;
    int wv   = tid >> 6;
    int lane = tid & 63;
    int quad = lane >> 4;
    int ln   = lane & 15;

    __shared__ __align__(16) short K_lds[T_K * K_STRIDE];
    __shared__ __align__(16) short Vt[DH * VT_STRIDE];
    __shared__ __align__(16) short Ps[4][16 * VT_STRIDE];
    __shared__ float sim_s[T_K];
    __shared__ int   idx_s[T_K];

    if (tid < T_K) {
        sim_s[tid] = sims[((size_t)b * S_DIM + s) * T_K + tid];
        idx_s[tid] = idx [((size_t)b * S_DIM + s) * T_K + tid];
    }
    __syncthreads();

    const short* qkvb = qkv + (size_t)b * HW * QKV_ST;
    int co = h * DH;

    {
        int r  = tid >> 1;
        int hh = tid & 1;
        const short* base = qkvb + (size_t)idx_s[r] * QKV_ST + co + hh * 16;
        short8 k0 = *(const short8*)(base + 256);
        short8 k1 = *(const short8*)(base + 256 + 8);
        *(short8*)&K_lds[r * K_STRIDE + hh * 16]     = k0;
        *(short8*)&K_lds[r * K_STRIDE + hh * 16 + 8] = k1;
        short8 v0 = *(const short8*)(base + 512);
        short8 v1 = *(const short8*)(base + 512 + 8);
#pragma unroll
        for (int i = 0; i < 8; i++) Vt[(hh * 16 + i) * VT_STRIDE + r]     = v0[i];
#pragma unroll
        for (int i = 0; i < 8; i++) Vt[(hh * 16 + 8 + i) * VT_STRIDE + r] = v1[i];
    }

    short8 aq[2];
#pragma unroll
    for (int mt = 0; mt < 2; mt++) {
        int t = wv * 32 + mt * 16 + ln;
        aq[mt] = *(const short8*)(qkvb + (size_t)idx_s[t] * QKV_ST + co + quad * 8);
    }
    __syncthreads();

    f32x4 S[2][8];
    const f32x4 zero4 = {0.f, 0.f, 0.f, 0.f};
#pragma unroll
    for (int nt = 0; nt < 8; nt++) {
        short8 kf = *(const short8*)&K_lds[(nt * 16 + ln) * K_STRIDE + quad * 8];
        S[0][nt] = __builtin_amdgcn_mfma_f32_16x16x32_bf16(aq[0], kf, zero4, 0, 0, 0);
        S[1][nt] = __builtin_amdgcn_mfma_f32_16x16x32_bf16(aq[1], kf, zero4, 0, 0, 0);
    }

    float lrow[2][4];
#pragma unroll
    for (int mt = 0; mt < 2; mt++) {
#pragma unroll
        for (int r = 0; r < 4; r++) {
            float mx = S[mt][0][r];
#pragma unroll
            for (int nt = 1; nt < 8; nt++) mx = fmaxf(mx, S[mt][nt][r]);
            mx = fmaxf(mx, __shfl_xor(mx, 1, 64));
            mx = fmaxf(mx, __shfl_xor(mx, 2, 64));
            mx = fmaxf(mx, __shfl_xor(mx, 4, 64));
            mx = fmaxf(mx, __shfl_xor(mx, 8, 64));
            float l = 0.f;
#pragma unroll
            for (int nt = 0; nt < 8; nt++) {
                float p = __expf((S[mt][nt][r] - mx) * SCALE_F);
                S[mt][nt][r] = p;
                l += p;
            }
            l += __shfl_xor(l, 1, 64);
            l += __shfl_xor(l, 2, 64);
            l += __shfl_xor(l, 4, 64);
            l += __shfl_xor(l, 8, 64);
            lrow[mt][r] = l;
        }
    }

    float* accb = acc + (size_t)b * HW * C_DIM + co;
#pragma unroll
    for (int mt = 0; mt < 2; mt++) {
        __syncthreads();
#pragma unroll
        for (int nt = 0; nt < 8; nt++) {
            float su = sim_s[nt * 16 + ln];
#pragma unroll
            for (int r = 0; r < 4; r++)
                Ps[wv][(quad * 4 + r) * VT_STRIDE + nt * 16 + ln] = f2bf(S[mt][nt][r] * su);
        }
        __syncthreads();

        f32x4 O[2] = {zero4, zero4};
#pragma unroll
        for (int kt = 0; kt < 4; kt++) {
            short8 pa = *(const short8*)&Ps[wv][ln * VT_STRIDE + kt * 32 + quad * 8];
#pragma unroll
            for (int nt2 = 0; nt2 < 2; nt2++) {
                short8 vb = *(const short8*)&Vt[(nt2 * 16 + ln) * VT_STRIDE + kt * 32 + quad * 8];
                O[nt2] = __builtin_amdgcn_mfma_f32_16x16x32_bf16(pa, vb, O[nt2], 0, 0, 0);
            }
        }
#pragma unroll
        for (int nt2 = 0; nt2 < 2; nt2++)
#pragma unroll
            for (int r = 0; r < 4; r++) {
                int t = wv * 32 + mt * 16 + quad * 4 + r;
                float val = O[nt2][r] * sim_s[t] / lrow[mt][r];
                atomicAdd(accb + (size_t)idx_s[t] * C_DIM + nt2 * 16 + ln, val);
            }
    }
}

// ---------------------------------------------------------------------------
// Kernel 5: out[b][c][n] = bf2f(v[b][n][c]) + acc[b][n][c]
__launch_bounds__(256)
__global__ void transpose_add_kernel(const short* __restrict__ qkv,
                                     const float* __restrict__ acc,
                                     float* __restrict__ out) {
    int b  = blockIdx.z;
    int n0 = blockIdx.x * 32;
    int c0 = blockIdx.y * 32;
    int x = threadIdx.x & 31;
    int y = threadIdx.x >> 5;

    __shared__ float t[32][33];
#pragma unroll
    for (int r = 0; r < 4; r++) {
        int n = n0 + y + 8 * r;
        size_t row = (size_t)b * HW + n;
        t[y + 8 * r][x] = bf2f(qkv[row * QKV_ST + 512 + c0 + x]) + acc[row * C_DIM + c0 + x];
    }
    __syncthreads();
#pragma unroll
    for (int r = 0; r < 4; r++) {
        int c = c0 + y + 8 * r;
        out[((size_t)b * C_DIM + c) * HW + n0 + x] = t[x][y + 8 * r];
    }
}

// ---------------------------------------------------------------------------
extern "C" void kernel_launch(void* const* d_in, const int* in_sizes, int n_in,
                              void* d_out, int out_size, void* d_ws, size_t ws_size,
                              hipStream_t stream) {
    const float* x    = (const float*)d_in[0];
    const float* aff  = (const float*)d_in[1];
    const float* g    = (const float*)d_in[2];
    const float* beta = (const float*)d_in[3];
    const float* wq   = (const float*)d_in[4];
    const float* wk   = (const float*)d_in[5];
    const float* wv   = (const float*)d_in[6];
    float* out = (float*)d_out;

    char* ws = (char*)d_ws;
    short* qkv  = (short*)ws;                                   ws += (size_t)B_DIM * HW * QKV_ST * 2;
    short* xnT  = (short*)ws;                                   ws += (size_t)B_DIM * HW * C_DIM * 2;
    short* wbuf = (short*)ws;                                   ws += (size_t)QKV_ST * C_DIM * 2;
    float* mu   = (float*)ws;                                   ws += (size_t)B_DIM * HW * 4;
    float* rsig = (float*)ws;                                   ws += (size_t)B_DIM * HW * 4;
    float* simsb= (float*)ws;                                   ws += (size_t)B_DIM * S_DIM * T_K * 4;
    int*   idxb = (int*)ws;                                     ws += (size_t)B_DIM * S_DIM * T_K * 4;
    float* acc  = (float*)ws;

    hipMemsetAsync(acc, 0, (size_t)B_DIM * HW * C_DIM * sizeof(float), stream);

    ln_stats_kernel<<<dim3(B_DIM * HW / 256), 256, 0, stream>>>(x, mu, rsig);
    wpack_kernel<<<dim3(QKV_ST * C_DIM / 4 / 256), 256, 0, stream>>>(wq, wk, wv, wbuf);
    xpack_kernel<<<dim3(HW / 64, C_DIM / 64, B_DIM), 256, 0, stream>>>(
        x, g, beta, mu, rsig, xnT);
    qkv_mfma_kernel<<<dim3(HW / 128, QKV_ST / 128, B_DIM), 256, 0, stream>>>(
        xnT, wbuf, qkv);
    topk_kernel<<<dim3(S_DIM, B_DIM), 256, 0, stream>>>(aff, simsb, idxb);
    attn_kernel<<<dim3(S_DIM, NH, B_DIM), 256, 0, stream>>>(qkv, simsb, idxb, acc);
    transpose_add_kernel<<<dim3(HW / 32, C_DIM / 32, B_DIM), 256, 0, stream>>>(
        qkv, acc, out);
}

// Round 7
// 307.767 us; speedup vs baseline: 4.7187x; 1.1372x over previous
//
#include <hip/hip_runtime.h>

#define HW      16384
#define C_DIM   256
#define S_DIM   256
#define T_K     128
#define NH      8
#define DH      32
#define QKV_ST  768
#define B_DIM   2
#define SCALE_F 0.17677669529663687f
#define CAND    1536
#define EQCAP   512

typedef __attribute__((ext_vector_type(8))) short short8;
typedef __attribute__((ext_vector_type(4))) float f32x4;

// round-to-nearest-even float -> bf16 (as short)
__device__ __forceinline__ short f2bf(float f) {
    unsigned u = __float_as_uint(f);
    unsigned r = (u + 0x7FFFu + ((u >> 16) & 1u)) >> 16;
    return (short)r;
}
__device__ __forceinline__ float bf2f(short s) {
    unsigned u = ((unsigned)(unsigned short)s) << 16;
    return __uint_as_float(u);
}

// sortable key: larger key <=> larger float (no NaNs in inputs)
__device__ __forceinline__ unsigned sortkey(float f) {
    unsigned u = __float_as_uint(f);
    return (u & 0x80000000u) ? ~u : (u | 0x80000000u);
}
__device__ __forceinline__ float keyval(unsigned k) {
    return __uint_as_float((k & 0x80000000u) ? (k ^ 0x80000000u) : ~k);
}

// wave-aggregated histogram add: one LDS atomic per distinct bin per wave
__device__ __forceinline__ void agg_hist_add(unsigned* hist, unsigned bin) {
    int lane = threadIdx.x & 63;
    unsigned long long rem = ~0ull;
    while (true) {
        int leader = __ffsll((unsigned long long)rem) - 1;
        unsigned lbin = __shfl(bin, leader, 64);
        unsigned long long eq = __ballot(bin == lbin);
        if (lane == leader) atomicAdd(&hist[lbin], (unsigned)__popcll(eq & rem));
        rem &= ~eq;
        if (rem == 0ull) break;
    }
}

// ---------------------------------------------------------------------------
// Kernel 1: per-pixel LN stats; 4 threads per pixel (quarter-C partials).
// Grid: B*HW/64 blocks of 256.
__launch_bounds__(256)
__global__ void ln_stats_kernel(const float* __restrict__ x,
                                float* __restrict__ mu,
                                float* __restrict__ rsig) {
    int q = threadIdx.x >> 6;        // 0..3  (channel quarter)
    int l = threadIdx.x & 63;        // pixel within block
    int p = blockIdx.x * 64 + l;
    int b = p >> 14;
    int n = p & (HW - 1);
    const float* xb = x + (size_t)b * C_DIM * HW + n;
    float s = 0.f, ss = 0.f;
#pragma unroll 8
    for (int c = q * 64; c < q * 64 + 64; c++) {
        float v = xb[(size_t)c * HW];
        s += v; ss += v * v;
    }
    __shared__ float ps[4][64], pss[4][64];
    ps[q][l] = s; pss[q][l] = ss;
    __syncthreads();
    if (threadIdx.x < 64) {
        float S  = ps[0][l] + ps[1][l] + ps[2][l] + ps[3][l];
        float SS = pss[0][l] + pss[1][l] + pss[2][l] + pss[3][l];
        float m   = S * (1.f / C_DIM);
        float var = fmaxf(SS * (1.f / C_DIM) - m * m, 0.f);
        int pp = blockIdx.x * 64 + l;
        mu[pp]   = m;
        rsig[pp] = rsqrtf(var + 1e-5f);
    }
}

// ---------------------------------------------------------------------------
// Kernel 1b: pack weights to bf16, layout Wb[o][c]
__global__ void wpack_kernel(const float* __restrict__ wq,
                             const float* __restrict__ wk,
                             const float* __restrict__ wv,
                             short* __restrict__ wb) {
    int gid  = blockIdx.x * 256 + threadIdx.x;
    int base = gid * 4;
    int o = base >> 8;
    int c = base & 255;
    const float* src = (o < 256) ? wq + (size_t)o * 256
                     : (o < 512) ? wk + (size_t)(o - 256) * 256
                                 : wv + (size_t)(o - 512) * 256;
    float4 w4 = *(const float4*)(src + c);
    short4 s4;
    s4.x = f2bf(w4.x); s4.y = f2bf(w4.y); s4.z = f2bf(w4.z); s4.w = f2bf(w4.w);
    *(short4*)&wb[base] = s4;
}

// ---------------------------------------------------------------------------
// Kernel 1c: LN-apply + transpose: xnT[b][n][c] = bf16(LN(x[b][c][n]))
__launch_bounds__(256)
__global__ void xpack_kernel(const float* __restrict__ x,
                             const float* __restrict__ g,
                             const float* __restrict__ beta,
                             const float* __restrict__ mu,
                             const float* __restrict__ rsig,
                             short* __restrict__ xnT) {
    int b  = blockIdx.z;
    int n0 = blockIdx.x * 64;
    int c0 = blockIdx.y * 64;
    int tid = threadIdx.x;

    __shared__ float t[64][65];

    {
        int cl = tid >> 2;
        int ni = (tid & 3) * 16;
        const float* src = x + ((size_t)b * C_DIM + c0 + cl) * HW + n0 + ni;
#pragma unroll
        for (int j = 0; j < 4; j++) {
            float4 v = *(const float4*)(src + j * 4);
            t[cl][ni + j * 4 + 0] = v.x;
            t[cl][ni + j * 4 + 1] = v.y;
            t[cl][ni + j * 4 + 2] = v.z;
            t[cl][ni + j * 4 + 3] = v.w;
        }
    }
    __syncthreads();

    {
        int nl = tid >> 2;
        int ci = (tid & 3) * 16;
        int n  = n0 + nl;
        float m  = mu[b * HW + n];
        float rs = rsig[b * HW + n];
        short8 s0, s1;
#pragma unroll
        for (int j = 0; j < 8; j++) {
            int c = c0 + ci + j;
            s0[j] = f2bf((t[ci + j][nl] - m) * rs * g[c] + beta[c]);
        }
#pragma unroll
        for (int j = 0; j < 8; j++) {
            int c = c0 + ci + 8 + j;
            s1[j] = f2bf((t[ci + 8 + j][nl] - m) * rs * g[c] + beta[c]);
        }
        short* dst = xnT + ((size_t)b * HW + n) * C_DIM + c0 + ci;
        *(short8*)(dst)     = s0;
        *(short8*)(dst + 8) = s1;
    }
}

// ---------------------------------------------------------------------------
// Kernel 2: bf16 MFMA QKV projection
#define E_STRIDE 136
__launch_bounds__(256)
__global__ void qkv_mfma_kernel(const short* __restrict__ xnT,
                                const short* __restrict__ wb,
                                short* __restrict__ qkv) {
    int b  = blockIdx.z;
    int n0 = blockIdx.x * 128;
    int o0 = blockIdx.y * 128;
    int tid  = threadIdx.x;
    int wv   = tid >> 6;
    int wn   = wv & 1;
    int wo   = wv >> 1;
    int lane = tid & 63;
    int quad = lane >> 4;
    int ln   = lane & 15;

    __shared__ __align__(16) short Es[128 * E_STRIDE];

    const short* arow[4];
    const short* brow[4];
#pragma unroll
    for (int mt = 0; mt < 4; mt++)
        arow[mt] = xnT + ((size_t)b * HW + n0 + wn * 64 + mt * 16 + ln) * C_DIM + quad * 8;
#pragma unroll
    for (int nt = 0; nt < 4; nt++)
        brow[nt] = wb + (size_t)(o0 + wo * 64 + nt * 16 + ln) * C_DIM + quad * 8;

    f32x4 acc[4][4];
    const f32x4 zero4 = {0.f, 0.f, 0.f, 0.f};
#pragma unroll
    for (int mt = 0; mt < 4; mt++)
#pragma unroll
        for (int nt = 0; nt < 4; nt++) acc[mt][nt] = zero4;

#pragma unroll 2
    for (int c0 = 0; c0 < C_DIM; c0 += 32) {
        short8 af[4], bf[4];
#pragma unroll
        for (int mt = 0; mt < 4; mt++) af[mt] = *(const short8*)(arow[mt] + c0);
#pragma unroll
        for (int nt = 0; nt < 4; nt++) bf[nt] = *(const short8*)(brow[nt] + c0);
#pragma unroll
        for (int mt = 0; mt < 4; mt++)
#pragma unroll
            for (int nt = 0; nt < 4; nt++)
                acc[mt][nt] = __builtin_amdgcn_mfma_f32_16x16x32_bf16(af[mt], bf[nt], acc[mt][nt], 0, 0, 0);
    }

#pragma unroll
    for (int mt = 0; mt < 4; mt++)
#pragma unroll
        for (int nt = 0; nt < 4; nt++)
#pragma unroll
            for (int r = 0; r < 4; r++)
                Es[(wn * 64 + mt * 16 + quad * 4 + r) * E_STRIDE + wo * 64 + nt * 16 + ln] =
                    f2bf(acc[mt][nt][r]);
    __syncthreads();

    {
        int nl   = tid >> 1;
        int half = tid & 1;
        const short* srcr = &Es[nl * E_STRIDE + half * 64];
        short* dst = qkv + ((size_t)b * HW + n0 + nl) * QKV_ST + o0 + half * 64;
#pragma unroll
        for (int j = 0; j < 8; j++)
            *(short8*)(dst + j * 8) = *(const short8*)(srcr + j * 8);
    }
}

// ---------------------------------------------------------------------------
// Kernel 3: exact top-128 per (b,s) row. 1024 threads (occupancy fix, R6).
// Race-free selection: uniform-register kneed/prefix; unique-writer s_sel.
__launch_bounds__(1024)
__global__ void topk_kernel(const float* __restrict__ aff,
                            float* __restrict__ sims,
                            int* __restrict__ idx) {
    int s = blockIdx.x, b = blockIdx.y;
    int tid = threadIdx.x;
    const float4* rowv4 = (const float4*)(aff + ((size_t)b * S_DIM + s) * HW);

    __shared__ unsigned hist[256];
    __shared__ unsigned sufs[256];
    __shared__ unsigned ckey[CAND];
    __shared__ int      cidx[CAND];
    __shared__ int      eqix[EQCAP];
    __shared__ int s_sel, cHi, cCand, cEq;

    if (tid == 0) { cHi = 0; cCand = 0; cEq = 0; }
    if (tid < 256) hist[tid] = 0;
    __syncthreads();

    // ---- pass 1: MSB-byte histogram over full row (wave-aggregated) ----
    for (int i = tid; i < HW / 4; i += 1024) {
        float4 v = rowv4[i];
        agg_hist_add(hist, sortkey(v.x) >> 24);
        agg_hist_add(hist, sortkey(v.y) >> 24);
        agg_hist_add(hist, sortkey(v.z) >> 24);
        agg_hist_add(hist, sortkey(v.w) >> 24);
    }
    __syncthreads();

    // ---- suffix scan (256 lanes active; barriers unconditional) ----
    if (tid < 256) sufs[tid] = hist[tid];
    __syncthreads();
#pragma unroll
    for (int off = 1; off < 256; off <<= 1) {
        unsigned v = 0;
        if (tid < 256 && tid + off < 256) v = sufs[tid + off];
        __syncthreads();
        if (tid < 256) sufs[tid] += v;
        __syncthreads();
    }

    int kneed = T_K;            // uniform register on every thread
    if (tid < 256) {
        unsigned above = (tid < 255) ? sufs[tid + 1] : 0u;
        if ((int)sufs[tid] >= kneed && (int)above < kneed) s_sel = tid;  // unique winner
    }
    __syncthreads();
    int sel = s_sel;            // uniform
    unsigned prefix = (unsigned)sel << 24;
    kneed -= (int)((sel < 255) ? sufs[sel + 1] : 0u);
    __syncthreads();

    float* so = sims + ((size_t)b * S_DIM + s) * T_K;
    int*   io = idx  + ((size_t)b * S_DIM + s) * T_K;

    // ---- pass 2: direct-emit above-bin, compact in-bin candidates ----
    for (int i = tid; i < HW / 4; i += 1024) {
        float4 v = rowv4[i];
        float vf[4] = {v.x, v.y, v.z, v.w};
#pragma unroll
        for (int j = 0; j < 4; j++) {
            unsigned u  = sortkey(vf[j]);
            unsigned hb = u >> 24;
            if (hb > (unsigned)sel) {
                int p = atomicAdd(&cHi, 1);
                so[p] = vf[j]; io[p] = i * 4 + j;
            } else if (hb == (unsigned)sel) {
                int c = atomicAdd(&cCand, 1);
                if (c < CAND) { ckey[c] = u; cidx[c] = i * 4 + j; }
            }
        }
    }
    __syncthreads();
    int nc = min(cCand, CAND);

    // ---- 3 radix refinements over candidates ----
    for (int shift = 16; shift >= 0; shift -= 8) {
        if (tid < 256) hist[tid] = 0;
        __syncthreads();
        unsigned mask = 0xFFFFFFFFu << (shift + 8);
        for (int i = tid; i < nc; i += 1024) {
            unsigned u = ckey[i];
            if ((u & mask) == prefix) atomicAdd(&hist[(u >> shift) & 255], 1u);
        }
        __syncthreads();
        if (tid < 256) sufs[tid] = hist[tid];
        __syncthreads();
#pragma unroll
        for (int off = 1; off < 256; off <<= 1) {
            unsigned v = 0;
            if (tid < 256 && tid + off < 256) v = sufs[tid + off];
            __syncthreads();
            if (tid < 256) sufs[tid] += v;
            __syncthreads();
        }
        if (tid < 256) {
            unsigned above = (tid < 255) ? sufs[tid + 1] : 0u;
            if ((int)sufs[tid] >= kneed && (int)above < kneed) s_sel = tid;
        }
        __syncthreads();
        sel = s_sel;
        prefix |= (unsigned)sel << shift;
        kneed  -= (int)((sel < 255) ? sufs[sel + 1] : 0u);
        __syncthreads();
    }

    unsigned T = prefix;        // exact 128th-largest key
    int kneedF = kneed;         // # of equal-to-T entries to keep (>=1)

    // ---- emit >T; compact ==T for deterministic tie resolution ----
    for (int i = tid; i < nc; i += 1024) {
        unsigned u = ckey[i];
        if (u > T) {
            int p = atomicAdd(&cHi, 1);
            so[p] = keyval(u); io[p] = cidx[i];
        } else if (u == T) {
            int q = atomicAdd(&cEq, 1);
            if (q < EQCAP) eqix[q] = cidx[i];
        }
    }
    __syncthreads();
    int m = min(cEq, EQCAP);

    // keep the kneedF SMALLEST indices among equals (jax tie order)
    float tval = keyval(T);
    for (int i = tid; i < m; i += 1024) {
        int my = eqix[i];
        int rank = 0;
        for (int j = 0; j < m; j++) rank += (eqix[j] < my);
        if (rank < kneedF) { so[127 - rank] = tval; io[127 - rank] = my; }
    }
}

// ---------------------------------------------------------------------------
// Kernel 4: MFMA attention per (b, s, h); qkv is bf16. sims folded into P.
#define K_STRIDE 40
#define VT_STRIDE 136
__launch_bounds__(256)
__global__ void attn_kernel(const short* __restrict__ qkv,
                            const float* __restrict__ sims,
                            const int* __restrict__ idx,
                            float* __restrict__ acc) {
    int s = blockIdx.x, h = blockIdx.y, b = blockIdx.z;
    int tid  = threadIdx.x;
    int wv   = tid >> 6;
    int lane = tid & 63;
    int quad = lane >> 4;
    int ln   = lane & 15;

    __shared__ __align__(16) short K_lds[T_K * K_STRIDE];
    __shared__ __align__(16) short Vt[DH * VT_STRIDE];
    __shared__ __align__(16) short Ps[4][16 * VT_STRIDE];
    __shared__ float sim_s[T_K];
    __shared__ int   idx_s[T_K];

    if (tid < T_K) {
        sim_s[tid] = sims[((size_t)b * S_DIM + s) * T_K + tid];
        idx_s[tid] = idx [((size_t)b * S_DIM + s) * T_K + tid];
    }
    __syncthreads();

    const short* qkvb = qkv + (size_t)b * HW * QKV_ST;
    int co = h * DH;

    {
        int r  = tid >> 1;
        int hh = tid & 1;
        const short* base = qkvb + (size_t)idx_s[r] * QKV_ST + co + hh * 16;
        short8 k0 = *(const short8*)(base + 256);
        short8 k1 = *(const short8*)(base + 256 + 8);
        *(short8*)&K_lds[r * K_STRIDE + hh * 16]     = k0;
        *(short8*)&K_lds[r * K_STRIDE + hh * 16 + 8] = k1;
        short8 v0 = *(const short8*)(base + 512);
        short8 v1 = *(const short8*)(base + 512 + 8);
#pragma unroll
        for (int i = 0; i < 8; i++) Vt[(hh * 16 + i) * VT_STRIDE + r]     = v0[i];
#pragma unroll
        for (int i = 0; i < 8; i++) Vt[(hh * 16 + 8 + i) * VT_STRIDE + r] = v1[i];
    }

    short8 aq[2];
#pragma unroll
    for (int mt = 0; mt < 2; mt++) {
        int t = wv * 32 + mt * 16 + ln;
        aq[mt] = *(const short8*)(qkvb + (size_t)idx_s[t] * QKV_ST + co + quad * 8);
    }
    __syncthreads();

    f32x4 S[2][8];
    const f32x4 zero4 = {0.f, 0.f, 0.f, 0.f};
#pragma unroll
    for (int nt = 0; nt < 8; nt++) {
        short8 kf = *(const short8*)&K_lds[(nt * 16 + ln) * K_STRIDE + quad * 8];
        S[0][nt] = __builtin_amdgcn_mfma_f32_16x16x32_bf16(aq[0], kf, zero4, 0, 0, 0);
        S[1][nt] = __builtin_amdgcn_mfma_f32_16x16x32_bf16(aq[1], kf, zero4, 0, 0, 0);
    }

    float lrow[2][4];
#pragma unroll
    for (int mt = 0; mt < 2; mt++) {
#pragma unroll
        for (int r = 0; r < 4; r++) {
            float mx = S[mt][0][r];
#pragma unroll
            for (int nt = 1; nt < 8; nt++) mx = fmaxf(mx, S[mt][nt][r]);
            mx = fmaxf(mx, __shfl_xor(mx, 1, 64));
            mx = fmaxf(mx, __shfl_xor(mx, 2, 64));
            mx = fmaxf(mx, __shfl_xor(mx, 4, 64));
            mx = fmaxf(mx, __shfl_xor(mx, 8, 64));
            float l = 0.f;
#pragma unroll
            for (int nt = 0; nt < 8; nt++) {
                float p = __expf((S[mt][nt][r] - mx) * SCALE_F);
                S[mt][nt][r] = p;
                l += p;
            }
            l += __shfl_xor(l, 1, 64);
            l += __shfl_xor(l, 2, 64);
            l += __shfl_xor(l, 4, 64);
            l += __shfl_xor(l, 8, 64);
            lrow[mt][r] = l;
        }
    }

    float* accb = acc + (size_t)b * HW * C_DIM + co;
#pragma unroll
    for (int mt = 0; mt < 2; mt++) {
        __syncthreads();
#pragma unroll
        for (int nt = 0; nt < 8; nt++) {
            float su = sim_s[nt * 16 + ln];
#pragma unroll
            for (int r = 0; r < 4; r++)
                Ps[wv][(quad * 4 + r) * VT_STRIDE + nt * 16 + ln] = f2bf(S[mt][nt][r] * su);
        }
        __syncthreads();

        f32x4 O[2] = {zero4, zero4};
#pragma unroll
        for (int kt = 0; kt < 4; kt++) {
            short8 pa = *(const short8*)&Ps[wv][ln * VT_STRIDE + kt * 32 + quad * 8];
#pragma unroll
            for (int nt2 = 0; nt2 < 2; nt2++) {
                short8 vb = *(const short8*)&Vt[(nt2 * 16 + ln) * VT_STRIDE + kt * 32 + quad * 8];
                O[nt2] = __builtin_amdgcn_mfma_f32_16x16x32_bf16(pa, vb, O[nt2], 0, 0, 0);
            }
        }
#pragma unroll
        for (int nt2 = 0; nt2 < 2; nt2++)
#pragma unroll
            for (int r = 0; r < 4; r++) {
                int t = wv * 32 + mt * 16 + quad * 4 + r;
                float val = O[nt2][r] * sim_s[t] / lrow[mt][r];
                atomicAdd(accb + (size_t)idx_s[t] * C_DIM + nt2 * 16 + ln, val);
            }
    }
}

// ---------------------------------------------------------------------------
// Kernel 5: out[b][c][n] = bf2f(v[b][n][c]) + acc[b][n][c]
__launch_bounds__(256)
__global__ void transpose_add_kernel(const short* __restrict__ qkv,
                                     const float* __restrict__ acc,
                                     float* __restrict__ out) {
    int b  = blockIdx.z;
    int n0 = blockIdx.x * 32;
    int c0 = blockIdx.y * 32;
    int x = threadIdx.x & 31;
    int y = threadIdx.x >> 5;

    __shared__ float t[32][33];
#pragma unroll
    for (int r = 0; r < 4; r++) {
        int n = n0 + y + 8 * r;
        size_t row = (size_t)b * HW + n;
        t[y + 8 * r][x] = bf2f(qkv[row * QKV_ST + 512 + c0 + x]) + acc[row * C_DIM + c0 + x];
    }
    __syncthreads();
#pragma unroll
    for (int r = 0; r < 4; r++) {
        int c = c0 + y + 8 * r;
        out[((size_t)b * C_DIM + c) * HW + n0 + x] = t[x][y + 8 * r];
    }
}

// ---------------------------------------------------------------------------
extern "C" void kernel_launch(void* const* d_in, const int* in_sizes, int n_in,
                              void* d_out, int out_size, void* d_ws, size_t ws_size,
                              hipStream_t stream) {
    const float* x    = (const float*)d_in[0];
    const float* aff  = (const float*)d_in[1];
    const float* g    = (const float*)d_in[2];
    const float* beta = (const float*)d_in[3];
    const float* wq   = (const float*)d_in[4];
    const float* wk   = (const float*)d_in[5];
    const float* wv   = (const float*)d_in[6];
    float* out = (float*)d_out;

    char* ws = (char*)d_ws;
    short* qkv  = (short*)ws;                                   ws += (size_t)B_DIM * HW * QKV_ST * 2;
    short* xnT  = (short*)ws;                                   ws += (size_t)B_DIM * HW * C_DIM * 2;
    short* wbuf = (short*)ws;                                   ws += (size_t)QKV_ST * C_DIM * 2;
    float* mu   = (float*)ws;                                   ws += (size_t)B_DIM * HW * 4;
    float* rsig = (float*)ws;                                   ws += (size_t)B_DIM * HW * 4;
    float* simsb= (float*)ws;                                   ws += (size_t)B_DIM * S_DIM * T_K * 4;
    int*   idxb = (int*)ws;                                     ws += (size_t)B_DIM * S_DIM * T_K * 4;
    float* acc  = (float*)ws;

    hipMemsetAsync(acc, 0, (size_t)B_DIM * HW * C_DIM * sizeof(float), stream);

    ln_stats_kernel<<<dim3(B_DIM * HW / 64), 256, 0, stream>>>(x, mu, rsig);
    wpack_kernel<<<dim3(QKV_ST * C_DIM / 4 / 256), 256, 0, stream>>>(wq, wk, wv, wbuf);
    xpack_kernel<<<dim3(HW / 64, C_DIM / 64, B_DIM), 256, 0, stream>>>(
        x, g, beta, mu, rsig, xnT);
    qkv_mfma_kernel<<<dim3(HW / 128, QKV_ST / 128, B_DIM), 256, 0, stream>>>(
        xnT, wbuf, qkv);
    topk_kernel<<<dim3(S_DIM, B_DIM), 1024, 0, stream>>>(aff, simsb, idxb);
    attn_kernel<<<dim3(S_DIM, NH, B_DIM), 256, 0, stream>>>(qkv, simsb, idxb, acc);
    transpose_add_kernel<<<dim3(HW / 32, C_DIM / 32, B_DIM), 256, 0, stream>>>(
        qkv, acc, out);
}